// Round 10
// baseline (143.515 us; speedup 1.0000x reference)
//
#include <hip/hip_runtime.h>
#include <hip/hip_bf16.h>

// Problem sizes (fixed by the reference)
#define B_  32
#define L_  512
#define D_  512
#define H_  8
#define HD_ 64

typedef __attribute__((ext_vector_type(8))) short bf16x8;   // 8 bf16 (4 VGPRs)
typedef __attribute__((ext_vector_type(4))) short bf16x4;
typedef __attribute__((ext_vector_type(4))) float f32x4;

__device__ __forceinline__ short f2bf(float f) {
  union { float f; unsigned u; } x; x.f = f;
  unsigned r = x.u + 0x7FFFu + ((x.u >> 16) & 1u);   // RNE truncation
  return (short)(r >> 16);
}

// async global->LDS, 16B per lane; dest base must be wave-uniform (HW adds lane*16)
__device__ __forceinline__ void gll16(const void* g, void* l) {
  __builtin_amdgcn_global_load_lds(
      (const __attribute__((address_space(1))) unsigned int*)g,
      (__attribute__((address_space(3))) unsigned int*)l, 16, 0, 0);
}

// 8x f32 -> bf16x8 via v_cvt_pk_bf16_f32 (compiler lowers __float22bfloat162_rn)
__device__ __forceinline__ bf16x8 cvt8(f32x4 a, f32x4 b) {
  union { __hip_bfloat162 h[4]; bf16x8 v; } u;
  u.h[0] = __float22bfloat162_rn(float2{a[0], a[1]});
  u.h[1] = __float22bfloat162_rn(float2{a[2], a[3]});
  u.h[2] = __float22bfloat162_rn(float2{b[0], b[1]});
  u.h[3] = __float22bfloat162_rn(float2{b[2], b[3]});
  return u.v;
}

// same-wave LDS write->read ordering fence (rule 18: sched_barrier after asm waitcnt)
#define DS_FENCE() do { asm volatile("s_waitcnt lgkmcnt(0)" ::: "memory"); \
                        __builtin_amdgcn_sched_barrier(0); } while (0)

// --------------------------------------------------------------------------
// Weight transpose + convert: wt[w][n][k] = bf16(W_w[k][n]), w = 0..3
// --------------------------------------------------------------------------
__global__ __launch_bounds__(256) void wt_kernel(
    const float* __restrict__ WQ, const float* __restrict__ WK,
    const float* __restrict__ WV, const float* __restrict__ WO,
    short* __restrict__ wt) {
  __shared__ float tile[32][33];
  int wz = blockIdx.z;
  const float* W = (wz == 0) ? WQ : (wz == 1) ? WK : (wz == 2) ? WV : WO;
  int k0 = blockIdx.y * 32, n0 = blockIdx.x * 32;
  int tr = threadIdx.x >> 5, tc = threadIdx.x & 31;
#pragma unroll
  for (int i = 0; i < 4; ++i)
    tile[tr + i * 8][tc] = W[(size_t)(k0 + tr + i * 8) * D_ + n0 + tc];
  __syncthreads();
#pragma unroll
  for (int i = 0; i < 4; ++i)
    wt[((size_t)wz * D_ + n0 + tr + i * 8) * D_ + k0 + tc] =
        f2bf(tile[tc][tr + i * 8]);
}

// --------------------------------------------------------------------------
// X f32 -> bf16 streaming conversion (one pass, ~150MB, BW-ceiling bound).
// xbf layout: [3][16384][512] bf16 (mode-major).
// --------------------------------------------------------------------------
__global__ __launch_bounds__(256) void xcvt_kernel(
    const float* __restrict__ Xq, const float* __restrict__ Xk,
    const float* __restrict__ Xv, short* __restrict__ xbf) {
  int mode = blockIdx.y;
  const float* X = (mode == 0) ? Xq : (mode == 1) ? Xk : Xv;
  short* dst = xbf + (size_t)mode * 8388608;
  size_t base = (size_t)blockIdx.x * 8192 + threadIdx.x * 8;
#pragma unroll
  for (int it = 0; it < 4; ++it) {
    size_t o = base + (size_t)it * 2048;
    f32x4 a = *(const f32x4*)(X + o);
    f32x4 b = *(const f32x4*)(X + o + 4);
    *(bf16x8*)(dst + o) = cvt8(a, b);
  }
}

// --------------------------------------------------------------------------
// QKV projection GEMM — 128x128 tile (m103: 128^2 = 2.7x the 64^2 rate at
// this structure), BK=64, all-bf16 all-gll16 staging (the R8-proven async
// path), measured-conflict-free swizzles. 4x4 acc. LDS 32KB.
// Output layouts: Q,K -> [b,h,l,hd] bf16; V -> [b,h,hd,l] bf16.
// --------------------------------------------------------------------------
__global__ __launch_bounds__(256, 4) void gemm_qkv(
    const short* __restrict__ xbf, const short* __restrict__ wt,
    const float* __restrict__ bQ, const float* __restrict__ bK,
    const float* __restrict__ bV,
    short* __restrict__ q_ws, short* __restrict__ k_ws,
    short* __restrict__ vt_ws) {
  __shared__ __align__(16) char lds[32768];
  char* Al = lds;            // bf16 [128 rows][128B]; slot s = chunk s^(row&7)
  char* Bl = lds + 16384;    // bf16 [128 rows][128B]; same rule

  int mode = blockIdx.z;
  const short* A = xbf + (size_t)mode * 8388608;
  const short* WT = wt + (size_t)mode * D_ * D_;
  const float* bias = (mode == 0) ? bQ : (mode == 1) ? bK : bV;

  // XCD swizzle (R3-proven): 4 n-tiles sharing A-rows land on one XCD.
  int wgid = blockIdx.x + 4 * blockIdx.y;   // 0..511, 512 % 8 == 0: bijective
  int rr_ = wgid >> 3;
  int m0 = ((wgid & 7) * 16 + (rr_ >> 2)) * 128;
  int n0 = (rr_ & 3) * 128;

  int tid = threadIdx.x, lane = tid & 63, w = tid >> 6;
  int wr = w >> 1, wc = w & 1, g = lane >> 4, lr = lane & 15;

  f32x4 acc[4][4] = {};

#pragma unroll
  for (int ks = 0; ks < 8; ++ks) {
    __syncthreads();   // WAR: prior step's reads done before DMA overwrite
    // stage A 16KB: 4 issues/wave (rows e*8..e*8+7, slot s = chunk s^(row&7))
#pragma unroll
    for (int j = 0; j < 4; ++j) {
      int e = w * 4 + j;
      int row = e * 8 + (lane >> 3);
      int chunk = (lane & 7) ^ (lane >> 3);
      gll16(A + (size_t)(m0 + row) * D_ + ks * 64 + chunk * 8, Al + e * 1024);
    }
    // stage B 16KB: 4 issues/wave, same pattern
#pragma unroll
    for (int j = 0; j < 4; ++j) {
      int e = w * 4 + j;
      int row = e * 8 + (lane >> 3);
      int chunk = (lane & 7) ^ (lane >> 3);
      gll16(WT + (size_t)(n0 + row) * D_ + ks * 64 + chunk * 8, Bl + e * 1024);
    }
    __syncthreads();   // drain: tiles ready
#pragma unroll
    for (int kk = 0; kk < 2; ++kk) {
      bf16x8 af[4], bf_[4];
#pragma unroll
      for (int i = 0; i < 4; ++i) {
        int row = wr * 64 + i * 16 + lr;            // row & 7 == lr & 7
        af[i] = *(const bf16x8*)(Al + row * 128 +
                                 (((kk * 4 + g) ^ (lr & 7)) << 4));
      }
#pragma unroll
      for (int i = 0; i < 4; ++i) {
        int row = wc * 64 + i * 16 + lr;
        bf_[i] = *(const bf16x8*)(Bl + row * 128 +
                                  (((kk * 4 + g) ^ (lr & 7)) << 4));
      }
#pragma unroll
      for (int mi = 0; mi < 4; ++mi)
#pragma unroll
        for (int nj = 0; nj < 4; ++nj)
          acc[mi][nj] = __builtin_amdgcn_mfma_f32_16x16x32_bf16(
              af[mi], bf_[nj], acc[mi][nj], 0, 0, 0);
    }
  }

  // Epilogue. C layout: row = g*4 + rr, col = lr (m89-verified).
#pragma unroll
  for (int mi = 0; mi < 4; ++mi) {
#pragma unroll
    for (int nj = 0; nj < 4; ++nj) {
      int n = n0 + wc * 64 + nj * 16 + lr;
      float bb = bias[n];
      int h = n >> 6, hd = n & 63;
#pragma unroll
      for (int rr = 0; rr < 4; ++rr) {
        int m = m0 + wr * 64 + mi * 16 + g * 4 + rr;
        int b = m >> 9, l = m & 511;
        short v = f2bf(acc[mi][nj][rr] + bb);
        if (mode == 0)
          q_ws[(((size_t)b * H_ + h) * L_ + l) * HD_ + hd] = v;
        else if (mode == 1)
          k_ws[(((size_t)b * H_ + h) * L_ + l) * HD_ + hd] = v;
        else
          vt_ws[(((size_t)b * H_ + h) * HD_ + hd) * L_ + l] = v;
      }
    }
  }
}

// --------------------------------------------------------------------------
// Attention, flash-style + T13 defer-max (R9-proven, ~28us): skip the O/sum
// rescale whenever __all(pmax - m <= 8). Softmax normalization cancels m.
// --------------------------------------------------------------------------
__global__ __launch_bounds__(256, 4) void attn_kernel(
    const short* __restrict__ q_ws, const short* __restrict__ k_ws,
    const short* __restrict__ vt_ws, const float* __restrict__ mask,
    short* __restrict__ ctx_ws) {
  __shared__ __align__(16) char lds[40960];
  int wg = blockIdx.x;                            // 2048 blocks, 2048%8==0
  int bh   = (wg & 7) * 32 + (wg >> 6);           // XCD-bijective: 32 heads/XCD
  int qblk = (wg >> 3) & 7;
  int b = bh >> 3, h = bh & 7;
  int tid = threadIdx.x, lane = tid & 63, w = tid >> 6;
  int g = lane >> 4, lr = lane & 15;
  char* Pl = lds + 32768 + w * 2048;              // per-wave P tile 16x64 bf16
  int qbase = qblk * 64 + w * 16;

  const short* Qh  = q_ws  + (size_t)bh * (L_ * HD_);
  const short* Kh  = k_ws  + (size_t)bh * (L_ * HD_);
  const short* VTh = vt_ws + (size_t)bh * (HD_ * L_);
  const float* mrow = mask + (size_t)b * L_;

  bf16x8 aq0 = *(const bf16x8*)(Qh + (size_t)(qbase + lr) * HD_ + g * 8);
  bf16x8 aq1 = *(const bf16x8*)(Qh + (size_t)(qbase + lr) * HD_ + 32 + g * 8);

  int rowin = lane >> 3;
  int sch8 = ((lane & 7) ^ rowin) * 8;   // pre-swizzled source offset (shorts)

#pragma unroll
  for (int j = 0; j < 2; ++j) {
    int e = w * 2 + j, row = e * 8 + rowin;
    gll16(Kh + (size_t)row * HD_ + sch8, lds + e * 1024);
    gll16(VTh + (size_t)row * L_ + sch8, lds + 16384 + e * 1024);
  }
  __syncthreads();

  f32x4 c[4] = {};
  float m[4] = {-1e30f, -1e30f, -1e30f, -1e30f};
  float sum[4] = {0.f, 0.f, 0.f, 0.f};

  for (int ch = 0; ch < 8; ++ch) {
    const char* Kb = lds + (ch & 1) * 8192;
    const char* Vb = lds + 16384 + (ch & 1) * 8192;
    if (ch < 7) {  // issue next chunk's stage first: overlaps this compute
      char* Kn = lds + ((ch + 1) & 1) * 8192;
      char* Vn = lds + 16384 + ((ch + 1) & 1) * 8192;
#pragma unroll
      for (int j = 0; j < 2; ++j) {
        int e = w * 2 + j, row = e * 8 + rowin;
        gll16(Kh + ((size_t)(ch + 1) * 64 + row) * HD_ + sch8, Kn + e * 1024);
        gll16(VTh + (size_t)row * L_ + (ch + 1) * 64 + sch8, Vn + e * 1024);
      }
    }
    float mb[4];
#pragma unroll
    for (int kt = 0; kt < 4; ++kt)
      mb[kt] = (1.0f - mrow[ch * 64 + kt * 16 + lr]) * -1e9f;

    f32x4 s[4];
#pragma unroll
    for (int kt = 0; kt < 4; ++kt) {
      int row = kt * 16 + lr;                      // row & 7 == lr & 7
      bf16x8 bk0 = *(const bf16x8*)(Kb + row * 128 + ((g ^ (lr & 7)) << 4));
      bf16x8 bk1 = *(const bf16x8*)(Kb + row * 128 + (((4 + g) ^ (lr & 7)) << 4));
      f32x4 a = {0.f, 0.f, 0.f, 0.f};
      a = __builtin_amdgcn_mfma_f32_16x16x32_bf16(aq0, bk0, a, 0, 0, 0);
      a = __builtin_amdgcn_mfma_f32_16x16x32_bf16(aq1, bk1, a, 0, 0, 0);
#pragma unroll
      for (int rr = 0; rr < 4; ++rr) a[rr] = a[rr] * 0.125f + mb[kt];
      s[kt] = a;
    }

    float pmax[4];
#pragma unroll
    for (int rr = 0; rr < 4; ++rr)
      pmax[rr] = fmaxf(fmaxf(s[0][rr], s[1][rr]), fmaxf(s[2][rr], s[3][rr]));
#pragma unroll
    for (int off = 1; off < 16; off <<= 1)
#pragma unroll
      for (int rr = 0; rr < 4; ++rr)
        pmax[rr] = fmaxf(pmax[rr], __shfl_xor(pmax[rr], off, 64));

    // T13 defer-max: rescale only when some row's max grew past THR=8
    int ok = (pmax[0] - m[0] <= 8.f) & (pmax[1] - m[1] <= 8.f) &
             (pmax[2] - m[2] <= 8.f) & (pmax[3] - m[3] <= 8.f);
    if (!__all(ok)) {
      float scl[4];
#pragma unroll
      for (int rr = 0; rr < 4; ++rr) {
        float mn = fmaxf(m[rr], pmax[rr]);
        scl[rr] = __expf(m[rr] - mn);
        m[rr] = mn;
        sum[rr] *= scl[rr];
      }
#pragma unroll
      for (int nt = 0; nt < 4; ++nt)
#pragma unroll
        for (int rr = 0; rr < 4; ++rr) c[nt][rr] *= scl[rr];
    }

#pragma unroll
    for (int kt = 0; kt < 4; ++kt) {
      int col2 = (kt * 16 + lr) * 2;
#pragma unroll
      for (int rr = 0; rr < 4; ++rr) {
        float p = __expf(s[kt][rr] - m[rr]);
        sum[rr] += p;
        int row = g * 4 + rr;
        *(short*)(Pl + row * 128 + (col2 ^ ((row & 7) << 4))) = f2bf(p);
      }
    }
    DS_FENCE();   // own-wave P writes visible before transposed reads

#pragma unroll
    for (int kk = 0; kk < 2; ++kk) {
      bf16x8 ap = *(const bf16x8*)(Pl + lr * 128 +
                                   (((kk * 4 + g) ^ (lr & 7)) << 4));
#pragma unroll
      for (int nt = 0; nt < 4; ++nt) {
        int row = nt * 16 + lr;
        bf16x8 bv = *(const bf16x8*)(Vb + row * 128 +
                                     (((kk * 4 + g) ^ (lr & 7)) << 4));
        c[nt] = __builtin_amdgcn_mfma_f32_16x16x32_bf16(ap, bv, c[nt], 0, 0, 0);
      }
    }
    DS_FENCE();   // P reads drained before next chunk's P writes (WAR)
    if (ch < 7) __syncthreads();   // next staged buffer ready for all waves
  }

  float inv[4];
#pragma unroll
  for (int off = 1; off < 16; off <<= 1)
#pragma unroll
    for (int rr = 0; rr < 4; ++rr) sum[rr] += __shfl_xor(sum[rr], off, 64);
#pragma unroll
  for (int rr = 0; rr < 4; ++rr) inv[rr] = 1.0f / sum[rr];

#pragma unroll
  for (int nt = 0; nt < 4; ++nt) {
    int hd = nt * 16 + lr;
#pragma unroll
    for (int rr = 0; rr < 4; ++rr) {
      int qrow = qbase + g * 4 + rr;
      ctx_ws[(((size_t)b * L_ + qrow) * H_ + h) * HD_ + hd] =
          f2bf(c[nt][rr] * inv[rr]);
    }
  }
}

// --------------------------------------------------------------------------
// Output GEMM — same 128x128 all-bf16 all-gll16 template.
// --------------------------------------------------------------------------
__global__ __launch_bounds__(256, 4) void gemm_out(
    const short* __restrict__ ctx, const short* __restrict__ wt3,
    const float* __restrict__ bO, float* __restrict__ out) {
  __shared__ __align__(16) char lds[32768];
  char* Al = lds;
  char* Bl = lds + 16384;
  int wgid = blockIdx.x + 4 * blockIdx.y;   // 0..511
  int rr_ = wgid >> 3;
  int m0 = ((wgid & 7) * 16 + (rr_ >> 2)) * 128;
  int n0 = (rr_ & 3) * 128;
  int tid = threadIdx.x, lane = tid & 63, w = tid >> 6;
  int wr = w >> 1, wc = w & 1, g = lane >> 4, lr = lane & 15;

  f32x4 acc[4][4] = {};

#pragma unroll
  for (int ks = 0; ks < 8; ++ks) {
    __syncthreads();
#pragma unroll
    for (int j = 0; j < 4; ++j) {
      int e = w * 4 + j;
      int row = e * 8 + (lane >> 3);
      int chunk = (lane & 7) ^ (lane >> 3);
      gll16(ctx + (size_t)(m0 + row) * D_ + ks * 64 + chunk * 8, Al + e * 1024);
    }
#pragma unroll
    for (int j = 0; j < 4; ++j) {
      int e = w * 4 + j;
      int row = e * 8 + (lane >> 3);
      int chunk = (lane & 7) ^ (lane >> 3);
      gll16(wt3 + (size_t)(n0 + row) * D_ + ks * 64 + chunk * 8, Bl + e * 1024);
    }
    __syncthreads();
#pragma unroll
    for (int kk = 0; kk < 2; ++kk) {
      bf16x8 af[4], bf_[4];
#pragma unroll
      for (int i = 0; i < 4; ++i) {
        int row = wr * 64 + i * 16 + lr;            // row & 7 == lr & 7
        af[i] = *(const bf16x8*)(Al + row * 128 +
                                 (((kk * 4 + g) ^ (lr & 7)) << 4));
      }
#pragma unroll
      for (int i = 0; i < 4; ++i) {
        int row = wc * 64 + i * 16 + lr;
        bf_[i] = *(const bf16x8*)(Bl + row * 128 +
                                  (((kk * 4 + g) ^ (lr & 7)) << 4));
      }
#pragma unroll
      for (int mi = 0; mi < 4; ++mi)
#pragma unroll
        for (int nj = 0; nj < 4; ++nj)
          acc[mi][nj] = __builtin_amdgcn_mfma_f32_16x16x32_bf16(
              af[mi], bf_[nj], acc[mi][nj], 0, 0, 0);
    }
  }
#pragma unroll
  for (int mi = 0; mi < 4; ++mi) {
#pragma unroll
    for (int nj = 0; nj < 4; ++nj) {
      int n = n0 + wc * 64 + nj * 16 + lr;
      float bb = bO[n];
#pragma unroll
      for (int rr = 0; rr < 4; ++rr) {
        int m = m0 + wr * 64 + mi * 16 + g * 4 + rr;
        out[(size_t)m * D_ + n] = acc[mi][nj][rr] + bb;
      }
    }
  }
}

// --------------------------------------------------------------------------
extern "C" void kernel_launch(void* const* d_in, const int* in_sizes, int n_in,
                              void* d_out, int out_size, void* d_ws,
                              size_t ws_size, hipStream_t stream) {
  const float* query = (const float*)d_in[0];
  const float* key   = (const float*)d_in[1];
  const float* value = (const float*)d_in[2];
  const float* mask  = (const float*)d_in[3];
  // d_in[4..8]: edge/path inputs — bias is constant along the softmax axis,
  // so it cancels exactly; unused.
  const float* WQ = (const float*)d_in[9];
  const float* bQ = (const float*)d_in[10];
  const float* WK = (const float*)d_in[11];
  const float* bK = (const float*)d_in[12];
  const float* WV = (const float*)d_in[13];
  const float* bV = (const float*)d_in[14];
  const float* WO = (const float*)d_in[15];
  const float* bO = (const float*)d_in[16];

  // ws layout (shorts): wt | q | k | vt | xbf (ctx aliases xbf: xbf dead
  // after gemm_qkv, ctx written by attn afterwards -> stream-ordered safe)
  short* ws  = (short*)d_ws;
  short* wt  = ws;                       // 1,048,576
  short* q   = ws + 1048576;
  short* k   = q + 8388608;
  short* vt  = k + 8388608;
  short* xbf = vt + 8388608;             // 25,165,824 shorts
  short* ctx = xbf;                      // alias
  float* out = (float*)d_out;            // total ws: ~103 MB (R8-proven size)

  wt_kernel<<<dim3(16, 16, 4), 256, 0, stream>>>(WQ, WK, WV, WO, wt);
  xcvt_kernel<<<dim3(1024, 3), 256, 0, stream>>>(query, key, value, xbf);
  gemm_qkv<<<dim3(4, 128, 3), 256, 0, stream>>>(xbf, wt, bQ, bK, bV, q, k, vt);
  attn_kernel<<<2048, 256, 0, stream>>>(q, k, vt, mask, ctx);
  gemm_out<<<dim3(4, 128), 256, 0, stream>>>(ctx, wt + 3 * 262144, bO, out);
}

// Round 11
// 130.891 us; speedup vs baseline: 1.0964x; 1.0964x over previous
//
#include <hip/hip_runtime.h>
#include <hip/hip_bf16.h>

// Problem sizes (fixed by the reference)
#define B_  32
#define L_  512
#define D_  512
#define H_  8
#define HD_ 64

typedef __attribute__((ext_vector_type(8))) short bf16x8;   // 8 bf16 (4 VGPRs)
typedef __attribute__((ext_vector_type(4))) short bf16x4;
typedef __attribute__((ext_vector_type(4))) float f32x4;

__device__ __forceinline__ short f2bf(float f) {
  union { float f; unsigned u; } x; x.f = f;
  unsigned r = x.u + 0x7FFFu + ((x.u >> 16) & 1u);   // RNE truncation
  return (short)(r >> 16);
}

// async global->LDS, 16B per lane; dest base must be wave-uniform (HW adds lane*16)
__device__ __forceinline__ void gll16(const void* g, void* l) {
  __builtin_amdgcn_global_load_lds(
      (const __attribute__((address_space(1))) unsigned int*)g,
      (__attribute__((address_space(3))) unsigned int*)l, 16, 0, 0);
}

// 8x f32 -> bf16x8 via v_cvt_pk_bf16_f32 (compiler lowers __float22bfloat162_rn)
__device__ __forceinline__ bf16x8 cvt8(f32x4 a, f32x4 b) {
  union { __hip_bfloat162 h[4]; bf16x8 v; } u;
  u.h[0] = __float22bfloat162_rn(float2{a[0], a[1]});
  u.h[1] = __float22bfloat162_rn(float2{a[2], a[3]});
  u.h[2] = __float22bfloat162_rn(float2{b[0], b[1]});
  u.h[3] = __float22bfloat162_rn(float2{b[2], b[3]});
  return u.v;
}

// same-wave LDS write->read ordering fence (rule 18: sched_barrier after asm waitcnt)
#define DS_FENCE() do { asm volatile("s_waitcnt lgkmcnt(0)" ::: "memory"); \
                        __builtin_amdgcn_sched_barrier(0); } while (0)

// --------------------------------------------------------------------------
// Weight transpose + convert: wt[w][n][k] = bf16(W_w[k][n]), w = 0..3
// --------------------------------------------------------------------------
__global__ __launch_bounds__(256) void wt_kernel(
    const float* __restrict__ WQ, const float* __restrict__ WK,
    const float* __restrict__ WV, const float* __restrict__ WO,
    short* __restrict__ wt) {
  __shared__ float tile[32][33];
  int wz = blockIdx.z;
  const float* W = (wz == 0) ? WQ : (wz == 1) ? WK : (wz == 2) ? WV : WO;
  int k0 = blockIdx.y * 32, n0 = blockIdx.x * 32;
  int tr = threadIdx.x >> 5, tc = threadIdx.x & 31;
#pragma unroll
  for (int i = 0; i < 4; ++i)
    tile[tr + i * 8][tc] = W[(size_t)(k0 + tr + i * 8) * D_ + n0 + tc];
  __syncthreads();
#pragma unroll
  for (int i = 0; i < 4; ++i)
    wt[((size_t)wz * D_ + n0 + tr + i * 8) * D_ + k0 + tc] =
        f2bf(tile[tc][tr + i * 8]);
}

// --------------------------------------------------------------------------
// QKV projection GEMM — R6-proven (best-total family): 64x128 tile, BK=64,
// single-buffer, A staged DIRECTLY as f32 via gll16 (X read exactly once,
// no xcvt round-trip), cvt at fragment load. Measured conflict-free
// swizzles (A 256B rows/16 slots, B 128B rows/8 slots). LDS 32KB.
// Output layouts: Q,K -> [b,h,l,hd] bf16; V -> [b,h,hd,l] bf16.
// --------------------------------------------------------------------------
__global__ __launch_bounds__(256, 4) void gemm_qkv(
    const float* __restrict__ Xq, const float* __restrict__ Xk,
    const float* __restrict__ Xv, const short* __restrict__ wt,
    const float* __restrict__ bQ, const float* __restrict__ bK,
    const float* __restrict__ bV,
    short* __restrict__ q_ws, short* __restrict__ k_ws,
    short* __restrict__ vt_ws) {
  __shared__ __align__(16) char lds[32768];   // A f32 [64][256B] | B bf16 [128][128B]
  char* Al = lds;
  char* Bl = lds + 16384;

  int mode = blockIdx.z;
  const float* A = (mode == 0) ? Xq : (mode == 1) ? Xk : Xv;
  const short* WT = wt + (size_t)mode * D_ * D_;
  const float* bias = (mode == 0) ? bQ : (mode == 1) ? bK : bV;

  // XCD swizzle: each XCD gets 32 consecutive m-tiles x 4 n-tiles.
  int wgid = blockIdx.x + 4 * blockIdx.y;   // 0..1023, 1024 % 8 == 0
  int xcd = wgid & 7, idx = wgid >> 3;
  int m0 = (xcd * 32 + (idx >> 2)) * 64;
  int n0 = (idx & 3) * 128;

  int tid = threadIdx.x, lane = tid & 63, w = tid >> 6;
  int wr = w >> 1, wc = w & 1, g = lane >> 4, lr = lane & 15;

  f32x4 acc[2][4] = {};

#pragma unroll
  for (int ks = 0; ks < 8; ++ks) {
    __syncthreads();   // WAR: prior step's reads done before DMA overwrite
    // stage A 16KB f32: 4 issues/wave; rows e*4..e*4+3 x 16 slots;
    // slot s of row holds f32-chunk s ^ (row&15)
#pragma unroll
    for (int j = 0; j < 4; ++j) {
      int e = w * 4 + j;
      int row = e * 4 + (lane >> 4);
      int chunk = (lane & 15) ^ (row & 15);
      gll16(A + (size_t)(m0 + row) * D_ + ks * 64 + chunk * 4, Al + e * 1024);
    }
    // stage B 16KB bf16: 4 issues/wave; rows e*8..e*8+7 x 8 slots;
    // slot s holds bf16-chunk s ^ (row&7)
#pragma unroll
    for (int j = 0; j < 4; ++j) {
      int e = w * 4 + j;
      int row = e * 8 + (lane >> 3);
      int chunk = (lane & 7) ^ (lane >> 3);
      gll16(WT + (size_t)(n0 + row) * D_ + ks * 64 + chunk * 8, Bl + e * 1024);
    }
    __syncthreads();   // drain: tiles ready (other resident blocks cover)
#pragma unroll
    for (int kk = 0; kk < 2; ++kk) {
      bf16x8 af[2], bf_[4];
#pragma unroll
      for (int i = 0; i < 2; ++i) {
        int row = wr * 32 + i * 16 + lr;            // row & 15 == lr
        int o0 = ((kk * 8 + g * 2) ^ lr) << 4;
        int o1 = ((kk * 8 + g * 2 + 1) ^ lr) << 4;
        f32x4 lo = *(const f32x4*)(Al + row * 256 + o0);
        f32x4 hi = *(const f32x4*)(Al + row * 256 + o1);
        af[i] = cvt8(lo, hi);
      }
#pragma unroll
      for (int i = 0; i < 4; ++i) {
        int row = wc * 64 + i * 16 + lr;            // row & 7 == lr & 7
        bf_[i] = *(const bf16x8*)(Bl + row * 128 +
                                  (((kk * 4 + g) ^ (lr & 7)) << 4));
      }
#pragma unroll
      for (int mi = 0; mi < 2; ++mi)
#pragma unroll
        for (int nj = 0; nj < 4; ++nj)
          acc[mi][nj] = __builtin_amdgcn_mfma_f32_16x16x32_bf16(
              af[mi], bf_[nj], acc[mi][nj], 0, 0, 0);
    }
  }

  // Epilogue. C layout: row = g*4 + rr, col = lr (m89-verified).
#pragma unroll
  for (int mi = 0; mi < 2; ++mi) {
#pragma unroll
    for (int nj = 0; nj < 4; ++nj) {
      int n = n0 + wc * 64 + nj * 16 + lr;
      float bb = bias[n];
      int h = n >> 6, hd = n & 63;
#pragma unroll
      for (int rr = 0; rr < 4; ++rr) {
        int m = m0 + wr * 32 + mi * 16 + g * 4 + rr;
        int b = m >> 9, l = m & 511;
        short v = f2bf(acc[mi][nj][rr] + bb);
        if (mode == 0)
          q_ws[(((size_t)b * H_ + h) * L_ + l) * HD_ + hd] = v;
        else if (mode == 1)
          k_ws[(((size_t)b * H_ + h) * L_ + l) * HD_ + hd] = v;
        else
          vt_ws[(((size_t)b * H_ + h) * HD_ + hd) * L_ + l] = v;
      }
    }
  }
}

// --------------------------------------------------------------------------
// Attention, flash-style + T13 defer-max (R9-proven, ~−25us vs rescale-every-
// chunk) + hoisted mask-bias loads + T5 setprio around MFMA clusters (m191).
// --------------------------------------------------------------------------
__global__ __launch_bounds__(256, 4) void attn_kernel(
    const short* __restrict__ q_ws, const short* __restrict__ k_ws,
    const short* __restrict__ vt_ws, const float* __restrict__ mask,
    short* __restrict__ ctx_ws) {
  __shared__ __align__(16) char lds[40960];
  int wg = blockIdx.x;                            // 2048 blocks, 2048%8==0
  int bh   = (wg & 7) * 32 + (wg >> 6);           // XCD-bijective: 32 heads/XCD
  int qblk = (wg >> 3) & 7;
  int b = bh >> 3, h = bh & 7;
  int tid = threadIdx.x, lane = tid & 63, w = tid >> 6;
  int g = lane >> 4, lr = lane & 15;
  char* Pl = lds + 32768 + w * 2048;              // per-wave P tile 16x64 bf16
  int qbase = qblk * 64 + w * 16;

  const short* Qh  = q_ws  + (size_t)bh * (L_ * HD_);
  const short* Kh  = k_ws  + (size_t)bh * (L_ * HD_);
  const short* VTh = vt_ws + (size_t)bh * (HD_ * L_);
  const float* mrow = mask + (size_t)b * L_;

  bf16x8 aq0 = *(const bf16x8*)(Qh + (size_t)(qbase + lr) * HD_ + g * 8);
  bf16x8 aq1 = *(const bf16x8*)(Qh + (size_t)(qbase + lr) * HD_ + 32 + g * 8);

  // hoisted mask bias: lane's 32 key columns (lr + 16*kt + 64*ch), registers
  float mb_all[32];
#pragma unroll
  for (int ch = 0; ch < 8; ++ch)
#pragma unroll
    for (int kt = 0; kt < 4; ++kt)
      mb_all[ch * 4 + kt] = (1.0f - mrow[ch * 64 + kt * 16 + lr]) * -1e9f;

  int rowin = lane >> 3;
  int sch8 = ((lane & 7) ^ rowin) * 8;   // pre-swizzled source offset (shorts)

#pragma unroll
  for (int j = 0; j < 2; ++j) {
    int e = w * 2 + j, row = e * 8 + rowin;
    gll16(Kh + (size_t)row * HD_ + sch8, lds + e * 1024);
    gll16(VTh + (size_t)row * L_ + sch8, lds + 16384 + e * 1024);
  }
  __syncthreads();

  f32x4 c[4] = {};
  float m[4] = {-1e30f, -1e30f, -1e30f, -1e30f};
  float sum[4] = {0.f, 0.f, 0.f, 0.f};

#pragma unroll
  for (int ch = 0; ch < 8; ++ch) {
    const char* Kb = lds + (ch & 1) * 8192;
    const char* Vb = lds + 16384 + (ch & 1) * 8192;
    if (ch < 7) {  // issue next chunk's stage first: overlaps this compute
      char* Kn = lds + ((ch + 1) & 1) * 8192;
      char* Vn = lds + 16384 + ((ch + 1) & 1) * 8192;
#pragma unroll
      for (int j = 0; j < 2; ++j) {
        int e = w * 2 + j, row = e * 8 + rowin;
        gll16(Kh + ((size_t)(ch + 1) * 64 + row) * HD_ + sch8, Kn + e * 1024);
        gll16(VTh + (size_t)row * L_ + (ch + 1) * 64 + sch8, Vn + e * 1024);
      }
    }

    f32x4 s[4];
    __builtin_amdgcn_s_setprio(1);
#pragma unroll
    for (int kt = 0; kt < 4; ++kt) {
      int row = kt * 16 + lr;                      // row & 7 == lr & 7
      bf16x8 bk0 = *(const bf16x8*)(Kb + row * 128 + ((g ^ (lr & 7)) << 4));
      bf16x8 bk1 = *(const bf16x8*)(Kb + row * 128 + (((4 + g) ^ (lr & 7)) << 4));
      f32x4 a = {0.f, 0.f, 0.f, 0.f};
      a = __builtin_amdgcn_mfma_f32_16x16x32_bf16(aq0, bk0, a, 0, 0, 0);
      a = __builtin_amdgcn_mfma_f32_16x16x32_bf16(aq1, bk1, a, 0, 0, 0);
#pragma unroll
      for (int rr = 0; rr < 4; ++rr)
        a[rr] = a[rr] * 0.125f + mb_all[ch * 4 + kt];
      s[kt] = a;
    }
    __builtin_amdgcn_s_setprio(0);

    float pmax[4];
#pragma unroll
    for (int rr = 0; rr < 4; ++rr)
      pmax[rr] = fmaxf(fmaxf(s[0][rr], s[1][rr]), fmaxf(s[2][rr], s[3][rr]));
#pragma unroll
    for (int off = 1; off < 16; off <<= 1)
#pragma unroll
      for (int rr = 0; rr < 4; ++rr)
        pmax[rr] = fmaxf(pmax[rr], __shfl_xor(pmax[rr], off, 64));

    // T13 defer-max: rescale only when some row's max grew past THR=8
    int ok = (pmax[0] - m[0] <= 8.f) & (pmax[1] - m[1] <= 8.f) &
             (pmax[2] - m[2] <= 8.f) & (pmax[3] - m[3] <= 8.f);
    if (!__all(ok)) {
      float scl[4];
#pragma unroll
      for (int rr = 0; rr < 4; ++rr) {
        float mn = fmaxf(m[rr], pmax[rr]);
        scl[rr] = __expf(m[rr] - mn);
        m[rr] = mn;
        sum[rr] *= scl[rr];
      }
#pragma unroll
      for (int nt = 0; nt < 4; ++nt)
#pragma unroll
        for (int rr = 0; rr < 4; ++rr) c[nt][rr] *= scl[rr];
    }

#pragma unroll
    for (int kt = 0; kt < 4; ++kt) {
      int col2 = (kt * 16 + lr) * 2;
#pragma unroll
      for (int rr = 0; rr < 4; ++rr) {
        float p = __expf(s[kt][rr] - m[rr]);
        sum[rr] += p;
        int row = g * 4 + rr;
        *(short*)(Pl + row * 128 + (col2 ^ ((row & 7) << 4))) = f2bf(p);
      }
    }
    DS_FENCE();   // own-wave P writes visible before transposed reads

    __builtin_amdgcn_s_setprio(1);
#pragma unroll
    for (int kk = 0; kk < 2; ++kk) {
      bf16x8 ap = *(const bf16x8*)(Pl + lr * 128 +
                                   (((kk * 4 + g) ^ (lr & 7)) << 4));
#pragma unroll
      for (int nt = 0; nt < 4; ++nt) {
        int row = nt * 16 + lr;
        bf16x8 bv = *(const bf16x8*)(Vb + row * 128 +
                                     (((kk * 4 + g) ^ (lr & 7)) << 4));
        c[nt] = __builtin_amdgcn_mfma_f32_16x16x32_bf16(ap, bv, c[nt], 0, 0, 0);
      }
    }
    __builtin_amdgcn_s_setprio(0);
    DS_FENCE();   // P reads drained before next chunk's P writes (WAR)
    if (ch < 7) __syncthreads();   // next staged buffer ready for all waves
  }

  float inv[4];
#pragma unroll
  for (int off = 1; off < 16; off <<= 1)
#pragma unroll
    for (int rr = 0; rr < 4; ++rr) sum[rr] += __shfl_xor(sum[rr], off, 64);
#pragma unroll
  for (int rr = 0; rr < 4; ++rr) inv[rr] = 1.0f / sum[rr];

#pragma unroll
  for (int nt = 0; nt < 4; ++nt) {
    int hd = nt * 16 + lr;
#pragma unroll
    for (int rr = 0; rr < 4; ++rr) {
      int qrow = qbase + g * 4 + rr;
      ctx_ws[(((size_t)b * L_ + qrow) * H_ + h) * HD_ + hd] =
          f2bf(c[nt][rr] * inv[rr]);
    }
  }
}

// --------------------------------------------------------------------------
// Output GEMM — 64x128 tile, single-buffer, BK=64, all-bf16 (R6-proven).
// LDS: A [64][128B] 8KB + B [128][128B] 16KB = 24KB -> 5-6 blocks/CU.
// --------------------------------------------------------------------------
__global__ __launch_bounds__(256, 4) void gemm_out(
    const short* __restrict__ ctx, const short* __restrict__ wt3,
    const float* __restrict__ bO, float* __restrict__ out) {
  __shared__ __align__(16) char lds[24576];
  char* Al = lds;
  char* Bl = lds + 8192;
  int wgid = blockIdx.x + 4 * blockIdx.y;   // 0..1023
  int xcd = wgid & 7, idx = wgid >> 3;
  int m0 = (xcd * 32 + (idx >> 2)) * 64;
  int n0 = (idx & 3) * 128;
  int tid = threadIdx.x, lane = tid & 63, w = tid >> 6;
  int wr = w >> 1, wc = w & 1, g = lane >> 4, lr = lane & 15;

  f32x4 acc[2][4] = {};

#pragma unroll
  for (int ks = 0; ks < 8; ++ks) {
    __syncthreads();
    // stage A 8KB: 2 issues/wave (rows e*8..e*8+7, 8 slots, chunk s^(row&7))
#pragma unroll
    for (int j = 0; j < 2; ++j) {
      int e = w * 2 + j;
      int row = e * 8 + (lane >> 3);
      int chunk = (lane & 7) ^ (lane >> 3);
      gll16(ctx + (size_t)(m0 + row) * D_ + ks * 64 + chunk * 8, Al + e * 1024);
    }
    // stage B 16KB: 4 issues/wave
#pragma unroll
    for (int j = 0; j < 4; ++j) {
      int e = w * 4 + j;
      int row = e * 8 + (lane >> 3);
      int chunk = (lane & 7) ^ (lane >> 3);
      gll16(wt3 + (size_t)(n0 + row) * D_ + ks * 64 + chunk * 8, Bl + e * 1024);
    }
    __syncthreads();
#pragma unroll
    for (int kk = 0; kk < 2; ++kk) {
      bf16x8 af[2], bf_[4];
#pragma unroll
      for (int i = 0; i < 2; ++i) {
        int row = wr * 32 + i * 16 + lr;            // row & 7 == lr & 7
        af[i] = *(const bf16x8*)(Al + row * 128 +
                                 (((kk * 4 + g) ^ (lr & 7)) << 4));
      }
#pragma unroll
      for (int i = 0; i < 4; ++i) {
        int row = wc * 64 + i * 16 + lr;
        bf_[i] = *(const bf16x8*)(Bl + row * 128 +
                                  (((kk * 4 + g) ^ (lr & 7)) << 4));
      }
#pragma unroll
      for (int mi = 0; mi < 2; ++mi)
#pragma unroll
        for (int nj = 0; nj < 4; ++nj)
          acc[mi][nj] = __builtin_amdgcn_mfma_f32_16x16x32_bf16(
              af[mi], bf_[nj], acc[mi][nj], 0, 0, 0);
    }
  }
#pragma unroll
  for (int mi = 0; mi < 2; ++mi) {
#pragma unroll
    for (int nj = 0; nj < 4; ++nj) {
      int n = n0 + wc * 64 + nj * 16 + lr;
      float bb = bO[n];
#pragma unroll
      for (int rr = 0; rr < 4; ++rr) {
        int m = m0 + wr * 32 + mi * 16 + g * 4 + rr;
        out[(size_t)m * D_ + n] = acc[mi][nj][rr] + bb;
      }
    }
  }
}

// --------------------------------------------------------------------------
extern "C" void kernel_launch(void* const* d_in, const int* in_sizes, int n_in,
                              void* d_out, int out_size, void* d_ws,
                              size_t ws_size, hipStream_t stream) {
  const float* query = (const float*)d_in[0];
  const float* key   = (const float*)d_in[1];
  const float* value = (const float*)d_in[2];
  const float* mask  = (const float*)d_in[3];
  // d_in[4..8]: edge/path inputs — bias is constant along the softmax axis,
  // so it cancels exactly; unused.
  const float* WQ = (const float*)d_in[9];
  const float* bQ = (const float*)d_in[10];
  const float* WK = (const float*)d_in[11];
  const float* bK = (const float*)d_in[12];
  const float* WV = (const float*)d_in[13];
  const float* bV = (const float*)d_in[14];
  const float* WO = (const float*)d_in[15];
  const float* bO = (const float*)d_in[16];

  // ws layout (shorts): wt | q | k | vt | ctx  (69.2 MB)
  short* ws  = (short*)d_ws;
  short* wt  = ws;                       // 1,048,576
  short* q   = ws + 1048576;
  short* k   = q + 8388608;
  short* vt  = k + 8388608;
  short* ctx = vt + 8388608;
  float* out = (float*)d_out;

  wt_kernel<<<dim3(16, 16, 4), 256, 0, stream>>>(WQ, WK, WV, WO, wt);
  gemm_qkv<<<dim3(4, 256, 3), 256, 0, stream>>>(query, key, value, wt,
                                                bQ, bK, bV, q, k, vt);
  attn_kernel<<<2048, 256, 0, stream>>>(q, k, vt, mask, ctx);
  gemm_out<<<dim3(4, 256), 256, 0, stream>>>(ctx, wt + 3 * 262144, bO, out);
}

// Round 12
// 128.951 us; speedup vs baseline: 1.1129x; 1.0150x over previous
//
#include <hip/hip_runtime.h>
#include <hip/hip_bf16.h>

// Problem sizes (fixed by the reference)
#define B_  32
#define L_  512
#define D_  512
#define H_  8
#define HD_ 64

typedef __attribute__((ext_vector_type(8))) short bf16x8;   // 8 bf16 (4 VGPRs)
typedef __attribute__((ext_vector_type(4))) short bf16x4;
typedef __attribute__((ext_vector_type(4))) float f32x4;

__device__ __forceinline__ short f2bf(float f) {
  union { float f; unsigned u; } x; x.f = f;
  unsigned r = x.u + 0x7FFFu + ((x.u >> 16) & 1u);   // RNE truncation
  return (short)(r >> 16);
}

// async global->LDS, 16B per lane; dest base must be wave-uniform (HW adds lane*16)
__device__ __forceinline__ void gll16(const void* g, void* l) {
  __builtin_amdgcn_global_load_lds(
      (const __attribute__((address_space(1))) unsigned int*)g,
      (__attribute__((address_space(3))) unsigned int*)l, 16, 0, 0);
}

// 8x f32 -> bf16x8 via v_cvt_pk_bf16_f32 (compiler lowers __float22bfloat162_rn)
__device__ __forceinline__ bf16x8 cvt8(f32x4 a, f32x4 b) {
  union { __hip_bfloat162 h[4]; bf16x8 v; } u;
  u.h[0] = __float22bfloat162_rn(float2{a[0], a[1]});
  u.h[1] = __float22bfloat162_rn(float2{a[2], a[3]});
  u.h[2] = __float22bfloat162_rn(float2{b[0], b[1]});
  u.h[3] = __float22bfloat162_rn(float2{b[2], b[3]});
  return u.v;
}

// same-wave LDS write->read ordering fence (rule 18: sched_barrier after asm waitcnt)
#define DS_FENCE() do { asm volatile("s_waitcnt lgkmcnt(0)" ::: "memory"); \
                        __builtin_amdgcn_sched_barrier(0); } while (0)

// --------------------------------------------------------------------------
// Weight transpose + convert: wt[w][n][k] = bf16(W_w[k][n]), w = 0..3
// --------------------------------------------------------------------------
__global__ __launch_bounds__(256) void wt_kernel(
    const float* __restrict__ WQ, const float* __restrict__ WK,
    const float* __restrict__ WV, const float* __restrict__ WO,
    short* __restrict__ wt) {
  __shared__ float tile[32][33];
  int wz = blockIdx.z;
  const float* W = (wz == 0) ? WQ : (wz == 1) ? WK : (wz == 2) ? WV : WO;
  int k0 = blockIdx.y * 32, n0 = blockIdx.x * 32;
  int tr = threadIdx.x >> 5, tc = threadIdx.x & 31;
#pragma unroll
  for (int i = 0; i < 4; ++i)
    tile[tr + i * 8][tc] = W[(size_t)(k0 + tr + i * 8) * D_ + n0 + tc];
  __syncthreads();
#pragma unroll
  for (int i = 0; i < 4; ++i)
    wt[((size_t)wz * D_ + n0 + tr + i * 8) * D_ + k0 + tc] =
        f2bf(tile[tc][tr + i * 8]);
}

// --------------------------------------------------------------------------
// QKV projection GEMM — 64x256 tile (staging-bytes-per-FLOP model: the
// 2-phase structure tracks staged KB/MFLOP; 48KB per 2.10 MFLOP = 22.9,
// matching R8's bf16 ratio WITHOUT the xcvt round-trip). A staged f32 via
// gll16 (X read once), cvt at fragment load. BK=64, single-buffer, proven
// swizzles. LDS 48KB -> 3 blocks/CU. acc 2x8.
// Output layouts: Q,K -> [b,h,l,hd] bf16; V -> [b,h,hd,l] bf16.
// --------------------------------------------------------------------------
__global__ __launch_bounds__(256, 3) void gemm_qkv(
    const float* __restrict__ Xq, const float* __restrict__ Xk,
    const float* __restrict__ Xv, const short* __restrict__ wt,
    const float* __restrict__ bQ, const float* __restrict__ bK,
    const float* __restrict__ bV,
    short* __restrict__ q_ws, short* __restrict__ k_ws,
    short* __restrict__ vt_ws) {
  __shared__ __align__(16) char lds[49152];
  char* Al = lds;            // f32 [64][256B]; slot s = chunk s^(row&15)
  char* Bl = lds + 16384;    // bf16 [256][128B]; slot s = chunk s^(row&7)

  int mode = blockIdx.z;
  const float* A = (mode == 0) ? Xq : (mode == 1) ? Xk : Xv;
  const short* WT = wt + (size_t)mode * D_ * D_;
  const float* bias = (mode == 0) ? bQ : (mode == 1) ? bK : bV;

  // XCD swizzle: each XCD gets 32 consecutive m-tiles x 2 n-tiles.
  int wgid = blockIdx.x + 2 * blockIdx.y;   // 0..511, 512 % 8 == 0
  int xcd = wgid & 7, idx = wgid >> 3;      // idx 0..63
  int m0 = (xcd * 32 + (idx >> 1)) * 64;
  int n0 = (idx & 1) * 256;

  int tid = threadIdx.x, lane = tid & 63, w = tid >> 6;
  int wr = w >> 1, wc = w & 1, g = lane >> 4, lr = lane & 15;

  f32x4 acc[2][8] = {};

#pragma unroll
  for (int ks = 0; ks < 8; ++ks) {
    __syncthreads();   // WAR: prior step's reads done before DMA overwrite
    // stage A 16KB f32: 4 issues/wave; rows e*4..e*4+3 x 16 slots;
    // slot s of row holds f32-chunk s ^ (row&15)   [proven pattern]
#pragma unroll
    for (int j = 0; j < 4; ++j) {
      int e = w * 4 + j;
      int row = e * 4 + (lane >> 4);
      int chunk = (lane & 15) ^ (row & 15);
      gll16(A + (size_t)(m0 + row) * D_ + ks * 64 + chunk * 4, Al + e * 1024);
    }
    // stage B 32KB bf16: 8 issues/wave; rows e*8..e*8+7 x 8 slots;
    // slot s holds bf16-chunk s ^ (row&7)          [proven pattern]
#pragma unroll
    for (int j = 0; j < 8; ++j) {
      int e = w * 8 + j;
      int row = e * 8 + (lane >> 3);
      int chunk = (lane & 7) ^ (lane >> 3);
      gll16(WT + (size_t)(n0 + row) * D_ + ks * 64 + chunk * 8, Bl + e * 1024);
    }
    __syncthreads();   // drain: tiles ready (other resident blocks cover)
#pragma unroll
    for (int kk = 0; kk < 2; ++kk) {
      bf16x8 af[2], bf_[8];
#pragma unroll
      for (int i = 0; i < 2; ++i) {
        int row = wr * 32 + i * 16 + lr;            // row & 15 == lr
        int o0 = ((kk * 8 + g * 2) ^ lr) << 4;
        int o1 = ((kk * 8 + g * 2 + 1) ^ lr) << 4;
        f32x4 lo = *(const f32x4*)(Al + row * 256 + o0);
        f32x4 hi = *(const f32x4*)(Al + row * 256 + o1);
        af[i] = cvt8(lo, hi);
      }
#pragma unroll
      for (int i = 0; i < 8; ++i) {
        int row = wc * 128 + i * 16 + lr;           // row & 7 == lr & 7
        bf_[i] = *(const bf16x8*)(Bl + row * 128 +
                                  (((kk * 4 + g) ^ (lr & 7)) << 4));
      }
#pragma unroll
      for (int mi = 0; mi < 2; ++mi)
#pragma unroll
        for (int nj = 0; nj < 8; ++nj)
          acc[mi][nj] = __builtin_amdgcn_mfma_f32_16x16x32_bf16(
              af[mi], bf_[nj], acc[mi][nj], 0, 0, 0);
    }
  }

  // Epilogue. C layout: row = g*4 + rr, col = lr (m89-verified).
#pragma unroll
  for (int mi = 0; mi < 2; ++mi) {
#pragma unroll
    for (int nj = 0; nj < 8; ++nj) {
      int n = n0 + wc * 128 + nj * 16 + lr;
      float bb = bias[n];
      int h = n >> 6, hd = n & 63;
#pragma unroll
      for (int rr = 0; rr < 4; ++rr) {
        int m = m0 + wr * 32 + mi * 16 + g * 4 + rr;
        int b = m >> 9, l = m & 511;
        short v = f2bf(acc[mi][nj][rr] + bb);
        if (mode == 0)
          q_ws[(((size_t)b * H_ + h) * L_ + l) * HD_ + hd] = v;
        else if (mode == 1)
          k_ws[(((size_t)b * H_ + h) * L_ + l) * HD_ + hd] = v;
        else
          vt_ws[(((size_t)b * H_ + h) * HD_ + hd) * L_ + l] = v;
      }
    }
  }
}

// --------------------------------------------------------------------------
// Attention, flash-style + T13 defer-max + hoisted mask-bias + T5 setprio
// (R11 form, unchanged — isolate the qkv variable).
// --------------------------------------------------------------------------
__global__ __launch_bounds__(256, 4) void attn_kernel(
    const short* __restrict__ q_ws, const short* __restrict__ k_ws,
    const short* __restrict__ vt_ws, const float* __restrict__ mask,
    short* __restrict__ ctx_ws) {
  __shared__ __align__(16) char lds[40960];
  int wg = blockIdx.x;                            // 2048 blocks, 2048%8==0
  int bh   = (wg & 7) * 32 + (wg >> 6);           // XCD-bijective: 32 heads/XCD
  int qblk = (wg >> 3) & 7;
  int b = bh >> 3, h = bh & 7;
  int tid = threadIdx.x, lane = tid & 63, w = tid >> 6;
  int g = lane >> 4, lr = lane & 15;
  char* Pl = lds + 32768 + w * 2048;              // per-wave P tile 16x64 bf16
  int qbase = qblk * 64 + w * 16;

  const short* Qh  = q_ws  + (size_t)bh * (L_ * HD_);
  const short* Kh  = k_ws  + (size_t)bh * (L_ * HD_);
  const short* VTh = vt_ws + (size_t)bh * (HD_ * L_);
  const float* mrow = mask + (size_t)b * L_;

  bf16x8 aq0 = *(const bf16x8*)(Qh + (size_t)(qbase + lr) * HD_ + g * 8);
  bf16x8 aq1 = *(const bf16x8*)(Qh + (size_t)(qbase + lr) * HD_ + 32 + g * 8);

  // hoisted mask bias: lane's 32 key columns (lr + 16*kt + 64*ch), registers
  float mb_all[32];
#pragma unroll
  for (int ch = 0; ch < 8; ++ch)
#pragma unroll
    for (int kt = 0; kt < 4; ++kt)
      mb_all[ch * 4 + kt] = (1.0f - mrow[ch * 64 + kt * 16 + lr]) * -1e9f;

  int rowin = lane >> 3;
  int sch8 = ((lane & 7) ^ rowin) * 8;   // pre-swizzled source offset (shorts)

#pragma unroll
  for (int j = 0; j < 2; ++j) {
    int e = w * 2 + j, row = e * 8 + rowin;
    gll16(Kh + (size_t)row * HD_ + sch8, lds + e * 1024);
    gll16(VTh + (size_t)row * L_ + sch8, lds + 16384 + e * 1024);
  }
  __syncthreads();

  f32x4 c[4] = {};
  float m[4] = {-1e30f, -1e30f, -1e30f, -1e30f};
  float sum[4] = {0.f, 0.f, 0.f, 0.f};

#pragma unroll
  for (int ch = 0; ch < 8; ++ch) {
    const char* Kb = lds + (ch & 1) * 8192;
    const char* Vb = lds + 16384 + (ch & 1) * 8192;
    if (ch < 7) {  // issue next chunk's stage first: overlaps this compute
      char* Kn = lds + ((ch + 1) & 1) * 8192;
      char* Vn = lds + 16384 + ((ch + 1) & 1) * 8192;
#pragma unroll
      for (int j = 0; j < 2; ++j) {
        int e = w * 2 + j, row = e * 8 + rowin;
        gll16(Kh + ((size_t)(ch + 1) * 64 + row) * HD_ + sch8, Kn + e * 1024);
        gll16(VTh + (size_t)row * L_ + (ch + 1) * 64 + sch8, Vn + e * 1024);
      }
    }

    f32x4 s[4];
    __builtin_amdgcn_s_setprio(1);
#pragma unroll
    for (int kt = 0; kt < 4; ++kt) {
      int row = kt * 16 + lr;                      // row & 7 == lr & 7
      bf16x8 bk0 = *(const bf16x8*)(Kb + row * 128 + ((g ^ (lr & 7)) << 4));
      bf16x8 bk1 = *(const bf16x8*)(Kb + row * 128 + (((4 + g) ^ (lr & 7)) << 4));
      f32x4 a = {0.f, 0.f, 0.f, 0.f};
      a = __builtin_amdgcn_mfma_f32_16x16x32_bf16(aq0, bk0, a, 0, 0, 0);
      a = __builtin_amdgcn_mfma_f32_16x16x32_bf16(aq1, bk1, a, 0, 0, 0);
#pragma unroll
      for (int rr = 0; rr < 4; ++rr)
        a[rr] = a[rr] * 0.125f + mb_all[ch * 4 + kt];
      s[kt] = a;
    }
    __builtin_amdgcn_s_setprio(0);

    float pmax[4];
#pragma unroll
    for (int rr = 0; rr < 4; ++rr)
      pmax[rr] = fmaxf(fmaxf(s[0][rr], s[1][rr]), fmaxf(s[2][rr], s[3][rr]));
#pragma unroll
    for (int off = 1; off < 16; off <<= 1)
#pragma unroll
      for (int rr = 0; rr < 4; ++rr)
        pmax[rr] = fmaxf(pmax[rr], __shfl_xor(pmax[rr], off, 64));

    // T13 defer-max: rescale only when some row's max grew past THR=8
    int ok = (pmax[0] - m[0] <= 8.f) & (pmax[1] - m[1] <= 8.f) &
             (pmax[2] - m[2] <= 8.f) & (pmax[3] - m[3] <= 8.f);
    if (!__all(ok)) {
      float scl[4];
#pragma unroll
      for (int rr = 0; rr < 4; ++rr) {
        float mn = fmaxf(m[rr], pmax[rr]);
        scl[rr] = __expf(m[rr] - mn);
        m[rr] = mn;
        sum[rr] *= scl[rr];
      }
#pragma unroll
      for (int nt = 0; nt < 4; ++nt)
#pragma unroll
        for (int rr = 0; rr < 4; ++rr) c[nt][rr] *= scl[rr];
    }

#pragma unroll
    for (int kt = 0; kt < 4; ++kt) {
      int col2 = (kt * 16 + lr) * 2;
#pragma unroll
      for (int rr = 0; rr < 4; ++rr) {
        float p = __expf(s[kt][rr] - m[rr]);
        sum[rr] += p;
        int row = g * 4 + rr;
        *(short*)(Pl + row * 128 + (col2 ^ ((row & 7) << 4))) = f2bf(p);
      }
    }
    DS_FENCE();   // own-wave P writes visible before transposed reads

    __builtin_amdgcn_s_setprio(1);
#pragma unroll
    for (int kk = 0; kk < 2; ++kk) {
      bf16x8 ap = *(const bf16x8*)(Pl + lr * 128 +
                                   (((kk * 4 + g) ^ (lr & 7)) << 4));
#pragma unroll
      for (int nt = 0; nt < 4; ++nt) {
        int row = nt * 16 + lr;
        bf16x8 bv = *(const bf16x8*)(Vb + row * 128 +
                                     (((kk * 4 + g) ^ (lr & 7)) << 4));
        c[nt] = __builtin_amdgcn_mfma_f32_16x16x32_bf16(ap, bv, c[nt], 0, 0, 0);
      }
    }
    __builtin_amdgcn_s_setprio(0);
    DS_FENCE();   // P reads drained before next chunk's P writes (WAR)
    if (ch < 7) __syncthreads();   // next staged buffer ready for all waves
  }

  float inv[4];
#pragma unroll
  for (int off = 1; off < 16; off <<= 1)
#pragma unroll
    for (int rr = 0; rr < 4; ++rr) sum[rr] += __shfl_xor(sum[rr], off, 64);
#pragma unroll
  for (int rr = 0; rr < 4; ++rr) inv[rr] = 1.0f / sum[rr];

#pragma unroll
  for (int nt = 0; nt < 4; ++nt) {
    int hd = nt * 16 + lr;
#pragma unroll
    for (int rr = 0; rr < 4; ++rr) {
      int qrow = qbase + g * 4 + rr;
      ctx_ws[(((size_t)b * L_ + qrow) * H_ + h) * HD_ + hd] =
          f2bf(c[nt][rr] * inv[rr]);
    }
  }
}

// --------------------------------------------------------------------------
// Output GEMM — 64x128 tile, single-buffer, BK=64, all-bf16 (R6-proven).
// LDS: A [64][128B] 8KB + B [128][128B] 16KB = 24KB -> 5-6 blocks/CU.
// --------------------------------------------------------------------------
__global__ __launch_bounds__(256, 4) void gemm_out(
    const short* __restrict__ ctx, const short* __restrict__ wt3,
    const float* __restrict__ bO, float* __restrict__ out) {
  __shared__ __align__(16) char lds[24576];
  char* Al = lds;
  char* Bl = lds + 8192;
  int wgid = blockIdx.x + 4 * blockIdx.y;   // 0..1023
  int xcd = wgid & 7, idx = wgid >> 3;
  int m0 = (xcd * 32 + (idx >> 2)) * 64;
  int n0 = (idx & 3) * 128;
  int tid = threadIdx.x, lane = tid & 63, w = tid >> 6;
  int wr = w >> 1, wc = w & 1, g = lane >> 4, lr = lane & 15;

  f32x4 acc[2][4] = {};

#pragma unroll
  for (int ks = 0; ks < 8; ++ks) {
    __syncthreads();
    // stage A 8KB: 2 issues/wave (rows e*8..e*8+7, 8 slots, chunk s^(row&7))
#pragma unroll
    for (int j = 0; j < 2; ++j) {
      int e = w * 2 + j;
      int row = e * 8 + (lane >> 3);
      int chunk = (lane & 7) ^ (lane >> 3);
      gll16(ctx + (size_t)(m0 + row) * D_ + ks * 64 + chunk * 8, Al + e * 1024);
    }
    // stage B 16KB: 4 issues/wave
#pragma unroll
    for (int j = 0; j < 4; ++j) {
      int e = w * 4 + j;
      int row = e * 8 + (lane >> 3);
      int chunk = (lane & 7) ^ (lane >> 3);
      gll16(wt3 + (size_t)(n0 + row) * D_ + ks * 64 + chunk * 8, Bl + e * 1024);
    }
    __syncthreads();
#pragma unroll
    for (int kk = 0; kk < 2; ++kk) {
      bf16x8 af[2], bf_[4];
#pragma unroll
      for (int i = 0; i < 2; ++i) {
        int row = wr * 32 + i * 16 + lr;            // row & 7 == lr & 7
        af[i] = *(const bf16x8*)(Al + row * 128 +
                                 (((kk * 4 + g) ^ (lr & 7)) << 4));
      }
#pragma unroll
      for (int i = 0; i < 4; ++i) {
        int row = wc * 64 + i * 16 + lr;
        bf_[i] = *(const bf16x8*)(Bl + row * 128 +
                                  (((kk * 4 + g) ^ (lr & 7)) << 4));
      }
#pragma unroll
      for (int mi = 0; mi < 2; ++mi)
#pragma unroll
        for (int nj = 0; nj < 4; ++nj)
          acc[mi][nj] = __builtin_amdgcn_mfma_f32_16x16x32_bf16(
              af[mi], bf_[nj], acc[mi][nj], 0, 0, 0);
    }
  }
#pragma unroll
  for (int mi = 0; mi < 2; ++mi) {
#pragma unroll
    for (int nj = 0; nj < 4; ++nj) {
      int n = n0 + wc * 64 + nj * 16 + lr;
      float bb = bO[n];
#pragma unroll
      for (int rr = 0; rr < 4; ++rr) {
        int m = m0 + wr * 32 + mi * 16 + g * 4 + rr;
        out[(size_t)m * D_ + n] = acc[mi][nj][rr] + bb;
      }
    }
  }
}

// --------------------------------------------------------------------------
extern "C" void kernel_launch(void* const* d_in, const int* in_sizes, int n_in,
                              void* d_out, int out_size, void* d_ws,
                              size_t ws_size, hipStream_t stream) {
  const float* query = (const float*)d_in[0];
  const float* key   = (const float*)d_in[1];
  const float* value = (const float*)d_in[2];
  const float* mask  = (const float*)d_in[3];
  // d_in[4..8]: edge/path inputs — bias is constant along the softmax axis,
  // so it cancels exactly; unused.
  const float* WQ = (const float*)d_in[9];
  const float* bQ = (const float*)d_in[10];
  const float* WK = (const float*)d_in[11];
  const float* bK = (const float*)d_in[12];
  const float* WV = (const float*)d_in[13];
  const float* bV = (const float*)d_in[14];
  const float* WO = (const float*)d_in[15];
  const float* bO = (const float*)d_in[16];

  // ws layout (shorts): wt | q | k | vt | ctx  (69.2 MB)
  short* ws  = (short*)d_ws;
  short* wt  = ws;                       // 1,048,576
  short* q   = ws + 1048576;
  short* k   = q + 8388608;
  short* vt  = k + 8388608;
  short* ctx = vt + 8388608;
  float* out = (float*)d_out;

  wt_kernel<<<dim3(16, 16, 4), 256, 0, stream>>>(WQ, WK, WV, WO, wt);
  gemm_qkv<<<dim3(2, 256, 3), 256, 0, stream>>>(query, key, value, wt,
                                                bQ, bK, bV, q, k, vt);
  attn_kernel<<<2048, 256, 0, stream>>>(q, k, vt, mask, ctx);
  gemm_out<<<dim3(4, 256), 256, 0, stream>>>(ctx, wt + 3 * 262144, bO, out);
}